// Round 3
// baseline (123.225 us; speedup 1.0000x reference)
//
#include <hip/hip_runtime.h>
#include <math.h>

// Problem constants
#define NT 64
#define NQ 1024
#define NK 1024
// ws layout in floats:
//   KWpack : [1024][32] float4 (vb.x,vb.y,vb.z, sb)      @ 0       (131072 floats)
//   QFpack : [32][1024] float4 (v.x, v.y, v.z, sa)       @ 131072  (131072 floats)
//   wvtab  : [32][8]    (w1L,w2L,w3L,w1A,w2A,w3A,0,0)    @ 262144  (256 floats)
//   part   : [256][8]   per-block partial sums           @ 262400  (2048 floats)
#define WS_KW 0
#define WS_QF 131072
#define WS_WV 262144
#define WS_PART 262400

__launch_bounds__(256)
__global__ void prep_kernel(const float* __restrict__ qfeat,     // [1024][160]
                            const float* __restrict__ keyfeat,   // [1024][160]
                            const float* __restrict__ Wkey,      // [160][160]
                            const float* __restrict__ WvL,       // [96][32]
                            const float* __restrict__ WvA,       // [96][32]
                            float* __restrict__ ws) {
  const int blk = blockIdx.x;
  const int tid = threadIdx.x;
  if (blk < 128) {
    // KWpack: row r of key_feat @ W_key, columns (64+3c, 65+3c, 66+3c, c)
    // Only these 128 of 160 output columns are ever consumed downstream.
    const int g = blk * 256 + tid;          // 0..32767
    const int r = g >> 5;
    const int c = g & 31;
    const float* kf = keyfeat + r * 160;
    const int c0 = 64 + 3 * c;
    float a0 = 0.f, a1 = 0.f, a2 = 0.f, a3 = 0.f;
#pragma unroll 4
    for (int k = 0; k < 160; ++k) {
      const float f = kf[k];
      const float* wr = Wkey + k * 160;
      a0 = fmaf(f, wr[c0 + 0], a0);
      a1 = fmaf(f, wr[c0 + 1], a1);
      a2 = fmaf(f, wr[c0 + 2], a2);
      a3 = fmaf(f, wr[c], a3);
    }
    reinterpret_cast<float4*>(ws + WS_KW)[g] = make_float4(a0, a1, a2, a3);
  } else if (blk < 256) {
    // QFpack: (v[p][c], sa[p][c]) stored [c][p] so main-kernel reads coalesce
    const int g = (blk - 128) * 256 + tid;  // 0..32767
    const int p = g >> 5;
    const int c = g & 31;
    const float* q = qfeat + p * 160;
    float4 out = make_float4(q[64 + 3 * c], q[65 + 3 * c], q[66 + 3 * c], q[c]);
    reinterpret_cast<float4*>(ws + WS_QF)[c * 1024 + p] = out;
  } else {
    // wv means: .mean(axis=-2) over the 32 output channels commutes with the
    // einsum, so each 96->32 channel mix collapses to one 96-vector.
    if (tid < 32) {
      const int c = tid;
      float m0 = 0.f, m1 = 0.f, m2 = 0.f, m3 = 0.f, m4 = 0.f, m5 = 0.f;
      for (int o = 0; o < 32; ++o) {
        m0 += WvL[c * 32 + o];
        m1 += WvL[(32 + c) * 32 + o];
        m2 += WvL[(64 + c) * 32 + o];
        m3 += WvA[c * 32 + o];
        m4 += WvA[(32 + c) * 32 + o];
        m5 += WvA[(64 + c) * 32 + o];
      }
      float* wv = ws + WS_WV + c * 8;
      const float s = 1.0f / 32.0f;
      wv[0] = m0 * s; wv[1] = m1 * s; wv[2] = m2 * s;
      wv[3] = m3 * s; wv[4] = m4 * s; wv[5] = m5 * s;
      wv[6] = 0.f; wv[7] = 0.f;
    }
  }
}

__launch_bounds__(256)
__global__ void main_kernel(const float* __restrict__ T,        // [64][7]
                            const float* __restrict__ qweight,  // [1024]
                            const float* __restrict__ qcoord,   // [1024][3]
                            const float* __restrict__ kcoord,   // [1024][3]
                            float* __restrict__ ws) {
  __shared__ float4 keys[1024];   // raw lab-frame keys (x,y,z,0) — t-independent
  __shared__ float red[4][8];
  const int tid = threadIdx.x;
  const int t = blockIdx.x >> 2;
  const int p = (blockIdx.x & 3) * 256 + tid;

  // Load + normalize quaternion (uniform per block)
  const float* Tt = T + t * 7;
  float qw = Tt[0], qx = Tt[1], qy = Tt[2], qz = Tt[3];
  const float Xx = Tt[4], Xy = Tt[5], Xz = Tt[6];
  const float rn = rsqrtf(qw * qw + qx * qx + qy * qy + qz * qz);
  qw *= rn; qx *= rn; qy *= rn; qz *= rn;
  const float ix = -qx, iy = -qy, iz = -qz;  // conjugate (inverse rotation)

  // Stage raw keys in LDS (broadcast-read later; t-independent)
  for (int j = 0; j < 4; ++j) {
    const int k = j * 256 + tid;
    keys[k] = make_float4(kcoord[k * 3 + 0], kcoord[k * 3 + 1], kcoord[k * 3 + 2], 0.f);
  }
  __syncthreads();

  // Local query coord
  const float qpx = qcoord[p * 3 + 0];
  const float qpy = qcoord[p * 3 + 1];
  const float qpz = qcoord[p * 3 + 2];

  // Lab-frame transformed query point: qc = quat_apply(q, qp) + X.
  // Subtract-first d2 below mirrors the reference's rounding structure,
  // keeping the argmin ordering statistic at ~ulp(d2) noise (the expanded
  // 0.5|k|^2 - qc.k form has ~1e-6 noise -> expected argmin mismatches).
  const float uvx0 = qy * qpz - qz * qpy;
  const float uvy0 = qz * qpx - qx * qpz;
  const float uvz0 = qx * qpy - qy * qpx;
  const float qcx = qpx + 2.0f * (qw * uvx0 + (qy * uvz0 - qz * uvy0)) + Xx;
  const float qcy = qpy + 2.0f * (qw * uvy0 + (qz * uvx0 - qx * uvz0)) + Xy;
  const float qcz = qpz + 2.0f * (qw * uvz0 + (qx * uvy0 - qy * uvx0)) + Xz;

  // NN search: argmin_k |qc - kk|^2, two independent chains for ILP
  float mv0 = 1e30f, mv1 = 1e30f;
  int mi0 = 0, mi1 = 0;
#pragma unroll 8
  for (int k = 0; k < 1024; k += 2) {
    const float4 K0 = keys[k];
    const float4 K1 = keys[k + 1];
    const float dx0 = qcx - K0.x, dy0 = qcy - K0.y, dz0 = qcz - K0.z;
    const float dx1 = qcx - K1.x, dy1 = qcy - K1.y, dz1 = qcz - K1.z;
    const float d0 = dx0 * dx0 + dy0 * dy0 + dz0 * dz0;
    const float d1 = dx1 * dx1 + dy1 * dy1 + dz1 * dz1;
    if (d0 < mv0) { mv0 = d0; mi0 = k; }
    if (d1 < mv1) { mv1 = d1; mi1 = k + 1; }
  }
  float mind2; int minidx;
  if (mv1 < mv0) { mind2 = mv1; minidx = mi1; }
  else           { mind2 = mv0; minidx = mi0; }

  const float env = expf(-sqrtf(mind2));

  // Feature math in the query-local frame:
  //   R^T[sa*vb + va'*sb + va' x vb] = sa*(R^T vb) + v*sb + v x (R^T vb)
  // where va' = R v. So rotate only the 32 key vectors; the final qinv
  // rotation of the reference disappears.
  const float4* kwrow = reinterpret_cast<const float4*>(ws + WS_KW) + minidx * 32;
  const float4* qfp   = reinterpret_cast<const float4*>(ws + WS_QF) + p;
  const float* wv = ws + WS_WV;
  float lx = 0.f, ly = 0.f, lz = 0.f, ax = 0.f, ay = 0.f, az = 0.f;
#pragma unroll 4
  for (int c = 0; c < 32; ++c) {
    const float4 B = kwrow[c];          // (vb lab-frame, sb), pre-env
    const float4 A = qfp[c * 1024];     // (v local-frame, sa)
    // vb' = R^T vb
    const float uvx = iy * B.z - iz * B.y;
    const float uvy = iz * B.x - ix * B.z;
    const float uvz = ix * B.y - iy * B.x;
    const float bx = B.x + 2.0f * (qw * uvx + (iy * uvz - iz * uvy));
    const float by = B.y + 2.0f * (qw * uvy + (iz * uvx - ix * uvz));
    const float bz = B.z + 2.0f * (qw * uvz + (ix * uvy - iy * uvx));
    // cross(v, vb')
    const float crx = A.y * bz - A.z * by;
    const float cry = A.z * bx - A.x * bz;
    const float crz = A.x * by - A.y * bx;
    const float* w6 = wv + c * 8;
    const float a1L = w6[0] * A.w, a2L = w6[1] * B.w, w3L = w6[2];
    const float a1A = w6[3] * A.w, a2A = w6[4] * B.w, w3A = w6[5];
    lx = fmaf(a1L, bx, fmaf(a2L, A.x, fmaf(w3L, crx, lx)));
    ly = fmaf(a1L, by, fmaf(a2L, A.y, fmaf(w3L, cry, ly)));
    lz = fmaf(a1L, bz, fmaf(a2L, A.z, fmaf(w3L, crz, lz)));
    ax = fmaf(a1A, bx, fmaf(a2A, A.x, fmaf(w3A, crx, ax)));
    ay = fmaf(a1A, by, fmaf(a2A, A.y, fmaf(w3A, cry, ay)));
    az = fmaf(a1A, bz, fmaf(a2A, A.z, fmaf(w3A, crz, az)));
  }
  // env scales kf linearly -> scales both dtp vector outputs linearly
  lx *= env; ly *= env; lz *= env;
  ax *= env; ay *= env; az *= env;

  // ang_orbital = qp x lin (local frame); weight by query_weight[p]
  const float wp = qweight[p];
  const float ox = qpy * lz - qpz * ly;
  const float oy = qpz * lx - qpx * lz;
  const float oz = qpx * ly - qpy * lx;
  float r0 = wp * lx, r1 = wp * ly, r2 = wp * lz;
  float r3 = wp * (ox + ax), r4 = wp * (oy + ay), r5 = wp * (oz + az);

  // Wave reduce (64 lanes), then block reduce across 4 waves.
#pragma unroll
  for (int m = 32; m >= 1; m >>= 1) {
    r0 += __shfl_xor(r0, m);
    r1 += __shfl_xor(r1, m);
    r2 += __shfl_xor(r2, m);
    r3 += __shfl_xor(r3, m);
    r4 += __shfl_xor(r4, m);
    r5 += __shfl_xor(r5, m);
  }
  const int wave = tid >> 6;
  const int lane = tid & 63;
  if (lane == 0) {
    red[wave][0] = r0; red[wave][1] = r1; red[wave][2] = r2;
    red[wave][3] = r3; red[wave][4] = r4; red[wave][5] = r5;
  }
  __syncthreads();
  if (tid < 6) {
    const float s = red[0][tid] + red[1][tid] + red[2][tid] + red[3][tid];
    ws[WS_PART + blockIdx.x * 8 + tid] = s;
  }
}

__launch_bounds__(64)
__global__ void final_kernel(const float* __restrict__ ws, float* __restrict__ out) {
  const int t = threadIdx.x;  // 64 threads, one per T row
  float a0 = 0.f, a1 = 0.f, a2 = 0.f, a3 = 0.f, a4 = 0.f, a5 = 0.f;
#pragma unroll
  for (int b = 0; b < 4; ++b) {
    const float* pr = ws + WS_PART + (t * 4 + b) * 8;
    a0 += pr[0]; a1 += pr[1]; a2 += pr[2];
    a3 += pr[3]; a4 += pr[4]; a5 += pr[5];
  }
  out[t * 3 + 0] = a0; out[t * 3 + 1] = a1; out[t * 3 + 2] = a2;
  out[192 + t * 3 + 0] = a3; out[192 + t * 3 + 1] = a4; out[192 + t * 3 + 2] = a5;
}

extern "C" void kernel_launch(void* const* d_in, const int* in_sizes, int n_in,
                              void* d_out, int out_size, void* d_ws, size_t ws_size,
                              hipStream_t stream) {
  const float* T   = (const float*)d_in[0];   // [64][7]
  const float* qw  = (const float*)d_in[1];   // [1024]
  const float* qf  = (const float*)d_in[2];   // [1024][160]
  const float* qc  = (const float*)d_in[3];   // [1024][3]
  const float* kc  = (const float*)d_in[4];   // [1024][3]
  const float* kf  = (const float*)d_in[5];   // [1024][160]
  const float* Wk  = (const float*)d_in[6];   // [160][160]
  const float* WvL = (const float*)d_in[8];   // [96][32]  (Ws_* are dead outputs)
  const float* WvA = (const float*)d_in[10];  // [96][32]
  float* out = (float*)d_out;
  float* ws  = (float*)d_ws;

  prep_kernel<<<257, 256, 0, stream>>>(qf, kf, Wk, WvL, WvA, ws);
  main_kernel<<<256, 256, 0, stream>>>(T, qw, qc, kc, ws);
  final_kernel<<<1, 64, 0, stream>>>(ws, out);
}

// Round 6
// 122.136 us; speedup vs baseline: 1.0089x; 1.0089x over previous
//
#include <hip/hip_runtime.h>
#include <math.h>

// Problem constants
#define NT 64
#define NQ 1024
#define NK 1024
// ws layout in floats:
//   KWpack : [1024][32] float4 (vb.x,vb.y,vb.z, sb)      @ 0       (131072 floats)
//   QFpack : [32][1024] float4 (v.x, v.y, v.z, sa)       @ 131072  (131072 floats)
//   wvtab  : [32][8]    (w1L,w2L,w3L,w1A,w2A,w3A,0,0)    @ 262144  (256 floats)
#define WS_KW 0
#define WS_QF 131072
#define WS_WV 262144

__launch_bounds__(256)
__global__ void prep_kernel(const float* __restrict__ qfeat,     // [1024][160]
                            const float* __restrict__ keyfeat,   // [1024][160]
                            const float* __restrict__ Wkey,      // [160][160]
                            const float* __restrict__ WvL,       // [96][32]
                            const float* __restrict__ WvA,       // [96][32]
                            float* __restrict__ ws,
                            float* __restrict__ out) {
  const int blk = blockIdx.x;
  const int tid = threadIdx.x;
  if (blk < 128) {
    // KWpack: row r of key_feat @ W_key, columns (64+3c, 65+3c, 66+3c, c)
    // Only these 128 of 160 output columns are ever consumed downstream.
    const int g = blk * 256 + tid;          // 0..32767
    const int r = g >> 5;
    const int c = g & 31;
    const float* kf = keyfeat + r * 160;
    const int c0 = 64 + 3 * c;
    float a0 = 0.f, a1 = 0.f, a2 = 0.f, a3 = 0.f;
#pragma unroll 4
    for (int k = 0; k < 160; ++k) {
      const float f = kf[k];
      const float* wr = Wkey + k * 160;
      a0 = fmaf(f, wr[c0 + 0], a0);
      a1 = fmaf(f, wr[c0 + 1], a1);
      a2 = fmaf(f, wr[c0 + 2], a2);
      a3 = fmaf(f, wr[c], a3);
    }
    reinterpret_cast<float4*>(ws + WS_KW)[g] = make_float4(a0, a1, a2, a3);
  } else if (blk < 256) {
    // QFpack: (v[p][c], sa[p][c]) stored [c][p] so main-kernel reads coalesce
    const int g = (blk - 128) * 256 + tid;  // 0..32767
    const int p = g >> 5;
    const int c = g & 31;
    const float* q = qfeat + p * 160;
    float4 o = make_float4(q[64 + 3 * c], q[65 + 3 * c], q[66 + 3 * c], q[c]);
    reinterpret_cast<float4*>(ws + WS_QF)[c * 1024 + p] = o;
  } else {
    // (a) zero d_out (harness poisons it 0xAA; main_kernel accumulates atomically)
    out[tid] = 0.f;
    if (tid < 128) out[256 + tid] = 0.f;
    // (b) wv means: .mean(axis=-2) over the 32 output channels commutes with
    // the einsum, so each 96->32 channel mix collapses to one 96-vector.
    if (tid < 32) {
      const int c = tid;
      float m0 = 0.f, m1 = 0.f, m2 = 0.f, m3 = 0.f, m4 = 0.f, m5 = 0.f;
      for (int o = 0; o < 32; ++o) {
        m0 += WvL[c * 32 + o];
        m1 += WvL[(32 + c) * 32 + o];
        m2 += WvL[(64 + c) * 32 + o];
        m3 += WvA[c * 32 + o];
        m4 += WvA[(32 + c) * 32 + o];
        m5 += WvA[(64 + c) * 32 + o];
      }
      float* wv = ws + WS_WV + c * 8;
      const float s = 1.0f / 32.0f;
      wv[0] = m0 * s; wv[1] = m1 * s; wv[2] = m2 * s;
      wv[3] = m3 * s; wv[4] = m4 * s; wv[5] = m5 * s;
      wv[6] = 0.f; wv[7] = 0.f;
    }
  }
}

__launch_bounds__(256)
__global__ void main_kernel(const float* __restrict__ T,        // [64][7]
                            const float* __restrict__ qweight,  // [1024]
                            const float* __restrict__ qcoord,   // [1024][3]
                            const float* __restrict__ kcoord,   // [1024][3]
                            const float* __restrict__ ws,
                            float* __restrict__ out) {
  __shared__ float4 keys[1024];   // raw lab-frame keys (x,y,z,0) — t-independent
  __shared__ float red[4][8];
  const int tid = threadIdx.x;
  const int t = blockIdx.x >> 2;
  const int p = (blockIdx.x & 3) * 256 + tid;

  // Load + normalize quaternion (uniform per block)
  const float* Tt = T + t * 7;
  float qw = Tt[0], qx = Tt[1], qy = Tt[2], qz = Tt[3];
  const float Xx = Tt[4], Xy = Tt[5], Xz = Tt[6];
  const float rn = rsqrtf(qw * qw + qx * qx + qy * qy + qz * qz);
  qw *= rn; qx *= rn; qy *= rn; qz *= rn;
  const float ix = -qx, iy = -qy, iz = -qz;  // conjugate (inverse rotation)

  // Stage raw keys in LDS (broadcast-read later; t-independent)
  for (int j = 0; j < 4; ++j) {
    const int k = j * 256 + tid;
    keys[k] = make_float4(kcoord[k * 3 + 0], kcoord[k * 3 + 1], kcoord[k * 3 + 2], 0.f);
  }
  __syncthreads();

  // Local query coord
  const float qpx = qcoord[p * 3 + 0];
  const float qpy = qcoord[p * 3 + 1];
  const float qpz = qcoord[p * 3 + 2];

  // Lab-frame transformed query point: qc = quat_apply(q, qp) + X.
  // Subtract-first d2 below mirrors the reference's rounding structure,
  // keeping the argmin ordering statistic at ~ulp(d2) noise (the expanded
  // 0.5|k|^2 - qc.k form has ~1e-6 noise -> expected argmin mismatches).
  const float uvx0 = qy * qpz - qz * qpy;
  const float uvy0 = qz * qpx - qx * qpz;
  const float uvz0 = qx * qpy - qy * qpx;
  const float qcx = qpx + 2.0f * (qw * uvx0 + (qy * uvz0 - qz * uvy0)) + Xx;
  const float qcy = qpy + 2.0f * (qw * uvy0 + (qz * uvx0 - qx * uvz0)) + Xy;
  const float qcz = qpz + 2.0f * (qw * uvz0 + (qx * uvy0 - qy * uvx0)) + Xz;

  // NN search: argmin_k |qc - kk|^2, two independent chains for ILP
  float mv0 = 1e30f, mv1 = 1e30f;
  int mi0 = 0, mi1 = 0;
#pragma unroll 8
  for (int k = 0; k < 1024; k += 2) {
    const float4 K0 = keys[k];
    const float4 K1 = keys[k + 1];
    const float dx0 = qcx - K0.x, dy0 = qcy - K0.y, dz0 = qcz - K0.z;
    const float dx1 = qcx - K1.x, dy1 = qcy - K1.y, dz1 = qcz - K1.z;
    const float d0 = dx0 * dx0 + dy0 * dy0 + dz0 * dz0;
    const float d1 = dx1 * dx1 + dy1 * dy1 + dz1 * dz1;
    if (d0 < mv0) { mv0 = d0; mi0 = k; }
    if (d1 < mv1) { mv1 = d1; mi1 = k + 1; }
  }
  float mind2; int minidx;
  if (mv1 < mv0) { mind2 = mv1; minidx = mi1; }
  else           { mind2 = mv0; minidx = mi0; }

  const float env = expf(-sqrtf(mind2));

  // Feature math in the query-local frame:
  //   R^T[sa*vb + va'*sb + va' x vb] = sa*(R^T vb) + v*sb + v x (R^T vb)
  // where va' = R v. So rotate only the 32 key vectors; the final qinv
  // rotation of the reference disappears.
  const float4* kwrow = reinterpret_cast<const float4*>(ws + WS_KW) + minidx * 32;
  const float4* qfp   = reinterpret_cast<const float4*>(ws + WS_QF) + p;
  const float* wv = ws + WS_WV;
  float lx = 0.f, ly = 0.f, lz = 0.f, ax = 0.f, ay = 0.f, az = 0.f;
#pragma unroll 4
  for (int c = 0; c < 32; ++c) {
    const float4 B = kwrow[c];          // (vb lab-frame, sb), pre-env
    const float4 A = qfp[c * 1024];     // (v local-frame, sa)
    // vb' = R^T vb
    const float uvx = iy * B.z - iz * B.y;
    const float uvy = iz * B.x - ix * B.z;
    const float uvz = ix * B.y - iy * B.x;
    const float bx = B.x + 2.0f * (qw * uvx + (iy * uvz - iz * uvy));
    const float by = B.y + 2.0f * (qw * uvy + (iz * uvx - ix * uvz));
    const float bz = B.z + 2.0f * (qw * uvz + (ix * uvy - iy * uvx));
    // cross(v, vb')
    const float crx = A.y * bz - A.z * by;
    const float cry = A.z * bx - A.x * bz;
    const float crz = A.x * by - A.y * bx;
    const float* w6 = wv + c * 8;
    const float a1L = w6[0] * A.w, a2L = w6[1] * B.w, w3L = w6[2];
    const float a1A = w6[3] * A.w, a2A = w6[4] * B.w, w3A = w6[5];
    lx = fmaf(a1L, bx, fmaf(a2L, A.x, fmaf(w3L, crx, lx)));
    ly = fmaf(a1L, by, fmaf(a2L, A.y, fmaf(w3L, cry, ly)));
    lz = fmaf(a1L, bz, fmaf(a2L, A.z, fmaf(w3L, crz, lz)));
    ax = fmaf(a1A, bx, fmaf(a2A, A.x, fmaf(w3A, crx, ax)));
    ay = fmaf(a1A, by, fmaf(a2A, A.y, fmaf(w3A, cry, ay)));
    az = fmaf(a1A, bz, fmaf(a2A, A.z, fmaf(w3A, crz, az)));
  }
  // env scales kf linearly -> scales both dtp vector outputs linearly
  lx *= env; ly *= env; lz *= env;
  ax *= env; ay *= env; az *= env;

  // ang_orbital = qp x lin (local frame); weight by query_weight[p]
  const float wp = qweight[p];
  const float ox = qpy * lz - qpz * ly;
  const float oy = qpz * lx - qpx * lz;
  const float oz = qpx * ly - qpy * lx;
  float r0 = wp * lx, r1 = wp * ly, r2 = wp * lz;
  float r3 = wp * (ox + ax), r4 = wp * (oy + ay), r5 = wp * (oz + az);

  // Wave reduce (64 lanes), then block reduce across 4 waves, then one
  // device-scope atomicAdd per component (4 blocks/T-row contend: trivial).
#pragma unroll
  for (int m = 32; m >= 1; m >>= 1) {
    r0 += __shfl_xor(r0, m);
    r1 += __shfl_xor(r1, m);
    r2 += __shfl_xor(r2, m);
    r3 += __shfl_xor(r3, m);
    r4 += __shfl_xor(r4, m);
    r5 += __shfl_xor(r5, m);
  }
  const int wave = tid >> 6;
  const int lane = tid & 63;
  if (lane == 0) {
    red[wave][0] = r0; red[wave][1] = r1; red[wave][2] = r2;
    red[wave][3] = r3; red[wave][4] = r4; red[wave][5] = r5;
  }
  __syncthreads();
  if (tid < 6) {
    const float s = red[0][tid] + red[1][tid] + red[2][tid] + red[3][tid];
    const int row = (tid < 3) ? (t * 3 + tid) : (192 + t * 3 + (tid - 3));
    atomicAdd(out + row, s);
  }
}

extern "C" void kernel_launch(void* const* d_in, const int* in_sizes, int n_in,
                              void* d_out, int out_size, void* d_ws, size_t ws_size,
                              hipStream_t stream) {
  const float* T   = (const float*)d_in[0];   // [64][7]
  const float* qw  = (const float*)d_in[1];   // [1024]
  const float* qf  = (const float*)d_in[2];   // [1024][160]
  const float* qc  = (const float*)d_in[3];   // [1024][3]
  const float* kc  = (const float*)d_in[4];   // [1024][3]
  const float* kf  = (const float*)d_in[5];   // [1024][160]
  const float* Wk  = (const float*)d_in[6];   // [160][160]
  const float* WvL = (const float*)d_in[8];   // [96][32]  (Ws_* are dead outputs)
  const float* WvA = (const float*)d_in[10];  // [96][32]
  float* out = (float*)d_out;
  float* ws  = (float*)d_ws;

  prep_kernel<<<257, 256, 0, stream>>>(qf, kf, Wk, WvL, WvA, ws, out);
  main_kernel<<<256, 256, 0, stream>>>(T, qw, qc, kc, ws, out);
}

// Round 7
// 112.408 us; speedup vs baseline: 1.0962x; 1.0865x over previous
//
#include <hip/hip_runtime.h>
#include <math.h>

// Problem constants
#define NT 64
#define NQ 1024
#define NK 1024
// ws layout in floats:
//   KWpack : [1024][32] float4 (vb.x,vb.y,vb.z, sb)      @ 0       (131072 floats)
//   QFpack : [32][1024] float4 (v.x, v.y, v.z, sa)       @ 131072  (131072 floats)
//   wvtab  : [32][8]    (w1L,w2L,w3L,w1A,w2A,w3A,0,0)    @ 262144  (256 floats)
#define WS_KW 0
#define WS_QF 131072
#define WS_WV 262144

__launch_bounds__(256)
__global__ void prep_kernel(const float* __restrict__ qfeat,     // [1024][160]
                            const float* __restrict__ keyfeat,   // [1024][160]
                            const float* __restrict__ Wkey,      // [160][160]
                            const float* __restrict__ WvL,       // [96][32]
                            const float* __restrict__ WvA,       // [96][32]
                            float* __restrict__ ws,
                            float* __restrict__ out) {
  const int blk = blockIdx.x;
  const int tid = threadIdx.x;
  if (blk < 128) {
    // KWpack: row r of key_feat @ W_key, columns (64+3c, 65+3c, 66+3c, c)
    // Only these 128 of 160 output columns are ever consumed downstream.
    const int g = blk * 256 + tid;          // 0..32767
    const int r = g >> 5;
    const int c = g & 31;
    const float* kf = keyfeat + r * 160;
    const int c0 = 64 + 3 * c;
    float a0 = 0.f, a1 = 0.f, a2 = 0.f, a3 = 0.f;
#pragma unroll 4
    for (int k = 0; k < 160; ++k) {
      const float f = kf[k];
      const float* wr = Wkey + k * 160;
      a0 = fmaf(f, wr[c0 + 0], a0);
      a1 = fmaf(f, wr[c0 + 1], a1);
      a2 = fmaf(f, wr[c0 + 2], a2);
      a3 = fmaf(f, wr[c], a3);
    }
    reinterpret_cast<float4*>(ws + WS_KW)[g] = make_float4(a0, a1, a2, a3);
  } else if (blk < 256) {
    // QFpack: (v[p][c], sa[p][c]) stored [c][p] so main-kernel reads coalesce
    const int g = (blk - 128) * 256 + tid;  // 0..32767
    const int p = g >> 5;
    const int c = g & 31;
    const float* q = qfeat + p * 160;
    float4 o = make_float4(q[64 + 3 * c], q[65 + 3 * c], q[66 + 3 * c], q[c]);
    reinterpret_cast<float4*>(ws + WS_QF)[c * 1024 + p] = o;
  } else {
    // (a) zero d_out (harness poisons it 0xAA; main_kernel accumulates atomically)
    out[tid] = 0.f;
    if (tid < 128) out[256 + tid] = 0.f;
    // (b) wv means: .mean(axis=-2) over the 32 output channels commutes with
    // the einsum, so each 96->32 channel mix collapses to one 96-vector.
    if (tid < 32) {
      const int c = tid;
      float m0 = 0.f, m1 = 0.f, m2 = 0.f, m3 = 0.f, m4 = 0.f, m5 = 0.f;
      for (int o = 0; o < 32; ++o) {
        m0 += WvL[c * 32 + o];
        m1 += WvL[(32 + c) * 32 + o];
        m2 += WvL[(64 + c) * 32 + o];
        m3 += WvA[c * 32 + o];
        m4 += WvA[(32 + c) * 32 + o];
        m5 += WvA[(64 + c) * 32 + o];
      }
      float* wv = ws + WS_WV + c * 8;
      const float s = 1.0f / 32.0f;
      wv[0] = m0 * s; wv[1] = m1 * s; wv[2] = m2 * s;
      wv[3] = m3 * s; wv[4] = m4 * s; wv[5] = m5 * s;
      wv[6] = 0.f; wv[7] = 0.f;
    }
  }
}

// 4 threads cooperate per (t,q) pair: sub = tid&3 scans keys k = sub + 4m,
// then butterfly-merges argmin and splits the 32-channel feature loop 8/thread.
// Grid: 1024 blocks (t = blk>>4, 64 pairs per block) -> 4 blocks/CU,
// 4 waves/SIMD for latency hiding (was 1 wave/SIMD at 42us, VALUBusy 41%).
__launch_bounds__(256)
__global__ void main_kernel(const float* __restrict__ T,        // [64][7]
                            const float* __restrict__ qweight,  // [1024]
                            const float* __restrict__ qcoord,   // [1024][3]
                            const float* __restrict__ kcoord,   // [1024][3]
                            const float* __restrict__ ws,
                            float* __restrict__ out) {
  __shared__ float4 keys[1024];   // raw lab-frame keys (x,y,z,0) — t-independent
  __shared__ float red[4][8];
  const int tid = threadIdx.x;
  const int t   = blockIdx.x >> 4;          // 0..63
  const int pg  = blockIdx.x & 15;          // pair-group within t
  const int p   = pg * 64 + (tid >> 2);     // query index 0..1023
  const int sub = tid & 3;                  // key-subset / channel-subset id

  // Load + normalize quaternion (uniform per block)
  const float* Tt = T + t * 7;
  float qw = Tt[0], qx = Tt[1], qy = Tt[2], qz = Tt[3];
  const float Xx = Tt[4], Xy = Tt[5], Xz = Tt[6];
  const float rn = rsqrtf(qw * qw + qx * qx + qy * qy + qz * qz);
  qw *= rn; qx *= rn; qy *= rn; qz *= rn;
  const float ix = -qx, iy = -qy, iz = -qz;  // conjugate (inverse rotation)

  // Stage raw keys in LDS
  for (int j = 0; j < 4; ++j) {
    const int k = j * 256 + tid;
    keys[k] = make_float4(kcoord[k * 3 + 0], kcoord[k * 3 + 1], kcoord[k * 3 + 2], 0.f);
  }
  __syncthreads();

  // Local query coord
  const float qpx = qcoord[p * 3 + 0];
  const float qpy = qcoord[p * 3 + 1];
  const float qpz = qcoord[p * 3 + 2];

  // Lab-frame transformed query point: qc = quat_apply(q, qp) + X.
  // Subtract-first d2 mirrors the reference's rounding structure, keeping the
  // argmin ordering statistic at ~ulp(d2) noise.
  const float uvx0 = qy * qpz - qz * qpy;
  const float uvy0 = qz * qpx - qx * qpz;
  const float uvz0 = qx * qpy - qy * qpx;
  const float qcx = qpx + 2.0f * (qw * uvx0 + (qy * uvz0 - qz * uvy0)) + Xx;
  const float qcy = qpy + 2.0f * (qw * uvy0 + (qz * uvx0 - qx * uvz0)) + Xy;
  const float qcz = qpz + 2.0f * (qw * uvz0 + (qx * uvy0 - qy * uvx0)) + Xz;

  // NN search over this thread's 256 keys (k = sub + 4m), dual chains for ILP.
  // Wave-wide, one step touches 8 consecutive float4s = 128B = all 32 banks
  // exactly once -> conflict-free broadcast reads.
  float mv0 = 1e30f, mv1 = 1e30f;
  int mi0 = 0, mi1 = 0;
#pragma unroll 8
  for (int m = 0; m < 256; m += 2) {
    const int k0 = sub + 4 * m;
    const int k1 = k0 + 4;
    const float4 K0 = keys[k0];
    const float4 K1 = keys[k1];
    const float dx0 = qcx - K0.x, dy0 = qcy - K0.y, dz0 = qcz - K0.z;
    const float dx1 = qcx - K1.x, dy1 = qcy - K1.y, dz1 = qcz - K1.z;
    const float d0 = dx0 * dx0 + dy0 * dy0 + dz0 * dz0;
    const float d1 = dx1 * dx1 + dy1 * dy1 + dz1 * dz1;
    if (d0 < mv0) { mv0 = d0; mi0 = k0; }
    if (d1 < mv1) { mv1 = d1; mi1 = k1; }
  }
  // chain merge (tie -> lower index, matching jnp.argmin)
  float mv = mv0; int mi = mi0;
  if (mv1 < mv || (mv1 == mv && mi1 < mi)) { mv = mv1; mi = mi1; }
  // 4-lane butterfly argmin merge
#pragma unroll
  for (int msk = 1; msk <= 2; msk <<= 1) {
    const float vo = __shfl_xor(mv, msk);
    const int   io = __shfl_xor(mi, msk);
    if (vo < mv || (vo == mv && io < mi)) { mv = vo; mi = io; }
  }
  const int minidx = mi;
  const float env = expf(-sqrtf(mv));

  // Feature math in the query-local frame, 8 channels per thread (c = 4*jj+sub
  // -> 4 lanes of a pair read consecutive float4s, coalesced):
  //   R^T[sa*vb + va'*sb + va' x vb] = sa*(R^T vb) + v*sb + v x (R^T vb)
  const float4* kwrow = reinterpret_cast<const float4*>(ws + WS_KW) + minidx * 32;
  const float4* qfp   = reinterpret_cast<const float4*>(ws + WS_QF) + p;
  const float* wv = ws + WS_WV;
  float lx = 0.f, ly = 0.f, lz = 0.f, ax = 0.f, ay = 0.f, az = 0.f;
#pragma unroll
  for (int jj = 0; jj < 8; ++jj) {
    const int c = 4 * jj + sub;
    const float4 B = kwrow[c];          // (vb lab-frame, sb), pre-env
    const float4 A = qfp[c * 1024];     // (v local-frame, sa)
    // vb' = R^T vb
    const float uvx = iy * B.z - iz * B.y;
    const float uvy = iz * B.x - ix * B.z;
    const float uvz = ix * B.y - iy * B.x;
    const float bx = B.x + 2.0f * (qw * uvx + (iy * uvz - iz * uvy));
    const float by = B.y + 2.0f * (qw * uvy + (iz * uvx - ix * uvz));
    const float bz = B.z + 2.0f * (qw * uvz + (ix * uvy - iy * uvx));
    // cross(v, vb')
    const float crx = A.y * bz - A.z * by;
    const float cry = A.z * bx - A.x * bz;
    const float crz = A.x * by - A.y * bx;
    const float* w6 = wv + c * 8;
    const float a1L = w6[0] * A.w, a2L = w6[1] * B.w, w3L = w6[2];
    const float a1A = w6[3] * A.w, a2A = w6[4] * B.w, w3A = w6[5];
    lx = fmaf(a1L, bx, fmaf(a2L, A.x, fmaf(w3L, crx, lx)));
    ly = fmaf(a1L, by, fmaf(a2L, A.y, fmaf(w3L, cry, ly)));
    lz = fmaf(a1L, bz, fmaf(a2L, A.z, fmaf(w3L, crz, lz)));
    ax = fmaf(a1A, bx, fmaf(a2A, A.x, fmaf(w3A, crx, ax)));
    ay = fmaf(a1A, by, fmaf(a2A, A.y, fmaf(w3A, cry, ay)));
    az = fmaf(a1A, bz, fmaf(a2A, A.z, fmaf(w3A, crz, az)));
  }
  // 4-lane butterfly sum of channel partials -> all 4 lanes hold full sums
#pragma unroll
  for (int msk = 1; msk <= 2; msk <<= 1) {
    lx += __shfl_xor(lx, msk); ly += __shfl_xor(ly, msk); lz += __shfl_xor(lz, msk);
    ax += __shfl_xor(ax, msk); ay += __shfl_xor(ay, msk); az += __shfl_xor(az, msk);
  }
  // env scales kf linearly -> scales both dtp vector outputs linearly
  lx *= env; ly *= env; lz *= env;
  ax *= env; ay *= env; az *= env;

  // ang_orbital = qp x lin (local frame); weight by query_weight[p].
  // All 4 lanes of a pair compute identical values; final sum is scaled 0.25.
  const float wp = qweight[p];
  const float ox = qpy * lz - qpz * ly;
  const float oy = qpz * lx - qpx * lz;
  const float oz = qpx * ly - qpy * lx;
  float r0 = wp * lx, r1 = wp * ly, r2 = wp * lz;
  float r3 = wp * (ox + ax), r4 = wp * (oy + ay), r5 = wp * (oz + az);

  // Wave reduce (64 lanes = 16 pairs x 4 identical lanes), block reduce, atomic.
#pragma unroll
  for (int m = 32; m >= 1; m >>= 1) {
    r0 += __shfl_xor(r0, m);
    r1 += __shfl_xor(r1, m);
    r2 += __shfl_xor(r2, m);
    r3 += __shfl_xor(r3, m);
    r4 += __shfl_xor(r4, m);
    r5 += __shfl_xor(r5, m);
  }
  const int wave = tid >> 6;
  const int lane = tid & 63;
  if (lane == 0) {
    red[wave][0] = r0; red[wave][1] = r1; red[wave][2] = r2;
    red[wave][3] = r3; red[wave][4] = r4; red[wave][5] = r5;
  }
  __syncthreads();
  if (tid < 6) {
    const float s = red[0][tid] + red[1][tid] + red[2][tid] + red[3][tid];
    const int row = (tid < 3) ? (t * 3 + tid) : (192 + t * 3 + (tid - 3));
    atomicAdd(out + row, s * 0.25f);   // 0.25: each pair counted by 4 lanes
  }
}

extern "C" void kernel_launch(void* const* d_in, const int* in_sizes, int n_in,
                              void* d_out, int out_size, void* d_ws, size_t ws_size,
                              hipStream_t stream) {
  const float* T   = (const float*)d_in[0];   // [64][7]
  const float* qw  = (const float*)d_in[1];   // [1024]
  const float* qf  = (const float*)d_in[2];   // [1024][160]
  const float* qc  = (const float*)d_in[3];   // [1024][3]
  const float* kc  = (const float*)d_in[4];   // [1024][3]
  const float* kf  = (const float*)d_in[5];   // [1024][160]
  const float* Wk  = (const float*)d_in[6];   // [160][160]
  const float* WvL = (const float*)d_in[8];   // [96][32]  (Ws_* are dead outputs)
  const float* WvA = (const float*)d_in[10];  // [96][32]
  float* out = (float*)d_out;
  float* ws  = (float*)d_ws;

  prep_kernel<<<257, 256, 0, stream>>>(qf, kf, Wk, WvL, WvA, ws, out);
  main_kernel<<<1024, 256, 0, stream>>>(T, qw, qc, kc, ws, out);
}